// Round 8
// baseline (684.575 us; speedup 1.0000x reference)
//
#include <hip/hip_runtime.h>
#include <hip/hip_bf16.h>
#include <math.h>

#define QN 8192
#define CN 64
#define SHOT 5
#define DN 512

#define THREADS 512
#define BQ 32                // queries per block -> grid 256 = 1 block/CU
#define CHUNK_D 128          // d's per staged chunk
#define NCHUNK (DN / CHUNK_D)

// --- proto kernel: proto[c][d] = mean over SHOT of y[c][s][d] ---
__global__ void proto_kernel(const float* __restrict__ y, float* __restrict__ proto) {
    int idx = blockIdx.x * blockDim.x + threadIdx.x;
    if (idx < CN * DN) {
        int c = idx >> 9;
        int d = idx & (DN - 1);
        float s = 0.f;
#pragma unroll
        for (int sh = 0; sh < SHOT; ++sh)
            s += y[(c * SHOT + sh) * DN + d];
        proto[idx] = s * (1.0f / SHOT);
    }
}

// --- round-7 kernel + pure-VALU amplification (diagnostic) ---
__global__ __launch_bounds__(THREADS, 2) void dist_kernel(
        const float* __restrict__ x,
        const float* __restrict__ proto,
        float* __restrict__ out) {
    __shared__ __align__(16) float lds[24576];     // 96 KiB
    float4* xb = (float4*)lds;                     // [2][1024] f4 = 32 KiB
    float4* pb = (float4*)lds + 2048;              // [2][2048] f4 = 64 KiB

    const int tid  = threadIdx.x;
    const int lane = tid & 63;
    const int wave = __builtin_amdgcn_readfirstlane(tid >> 6);
    const int q0   = blockIdx.x * BQ;
    const int qg   = lane >> 3;
    const int cg   = lane & 7;
    const int lhi  = lane >> 5;
    const int llo  = lane & 31;

    auto issue = [&](int k) {
        const int xo = (k & 1) << 10;
        const int po = (k & 1) << 11;
#pragma unroll
        for (int tt = 0; tt < 2; ++tt) {
            int t = wave * 2 + tt;
            int q = 2 * t + lhi;
            int col = llo ^ ((q >> 2) & 7);
            const float* src = x + (size_t)(q0 + q) * DN + k * CHUNK_D + col * 4;
            __builtin_amdgcn_global_load_lds(
                (const __attribute__((address_space(1))) void*)src,
                (__attribute__((address_space(3))) void*)(xb + xo + t * 64), 16, 0, 0);
        }
#pragma unroll
        for (int tt = 0; tt < 4; ++tt) {
            int t = wave * 4 + tt;
            int c = 2 * t + lhi;
            int col = llo ^ ((c >> 3) & 7);
            const float* src = proto + (size_t)c * DN + k * CHUNK_D + col * 4;
            __builtin_amdgcn_global_load_lds(
                (const __attribute__((address_space(1))) void*)src,
                (__attribute__((address_space(3))) void*)(pb + po + t * 64), 16, 0, 0);
        }
    };

    float acc[4][8];
    float acc2[4][8];
#pragma unroll
    for (int i = 0; i < 4; ++i)
#pragma unroll
        for (int j = 0; j < 8; ++j) { acc[i][j] = 0.f; acc2[i][j] = 0.f; }

    issue(0);
#pragma unroll 1
    for (int k = 0; k < NCHUNK; ++k) {
        if (k + 1 < NCHUNK) {
            issue(k + 1);
            asm volatile("s_waitcnt vmcnt(6)" ::: "memory");
        } else {
            asm volatile("s_waitcnt vmcnt(0)" ::: "memory");
        }
        __builtin_amdgcn_s_barrier();
        __builtin_amdgcn_sched_barrier(0);

        const float4* xc = xb + ((k & 1) << 10);
        const float4* pc = pb + ((k & 1) << 11);
#pragma unroll
        for (int ft = 0; ft < 4; ++ft) {
            const int f = wave * 4 + ft;
            float4 xf[4];
#pragma unroll
            for (int i = 0; i < 4; ++i)
                xf[i] = xc[(qg * 4 + i) * 32 + (f ^ qg)];
#pragma unroll
            for (int j = 0; j < 8; ++j) {
                float4 pf = pc[(cg * 8 + j) * 32 + (f ^ cg)];
#pragma unroll
                for (int i = 0; i < 4; ++i) {
                    acc[i][j] += fabsf(xf[i].x - pf.x) + fabsf(xf[i].y - pf.y)
                               + fabsf(xf[i].z - pf.z) + fabsf(xf[i].w - pf.w);
                    // --- diagnostic amplification: pure VALU on live registers,
                    // distinct coefficients defeat CSE; zero extra LDS/global.
#pragma unroll
                    for (int r = 0; r < 3; ++r) {
                        float cco = 2.0f + (float)r;
                        acc2[i][j] += (xf[i].x - cco * pf.x) + (xf[i].y - cco * pf.y)
                                    + (xf[i].z - cco * pf.z) + (xf[i].w - cco * pf.w);
                    }
                }
            }
        }
        __builtin_amdgcn_sched_barrier(0);
        __builtin_amdgcn_s_barrier();
    }

    // keep the amplification chains alive without touching output
    float sink = 0.f;
#pragma unroll
    for (int i = 0; i < 4; ++i)
#pragma unroll
        for (int j = 0; j < 8; ++j) sink += acc2[i][j];
    asm volatile("" : : "v"(sink));

    // --- reduce the 8 wave-partials in LDS, then fused softmax ---
    float* red = lds;                              // [8][32][65]
#pragma unroll
    for (int i = 0; i < 4; ++i)
#pragma unroll
        for (int j = 0; j < 8; ++j)
            red[(wave * 32 + qg * 4 + i) * 65 + cg * 8 + j] = acc[i][j];
    __syncthreads();

#pragma unroll
    for (int r = 0; r < 4; ++r) {
        int q = wave * 4 + r;
        float s = 0.f;
#pragma unroll
        for (int ww = 0; ww < 8; ++ww)
            s += red[(ww * 32 + q) * 65 + lane];
        float nd = -s;
        float m = nd;
#pragma unroll
        for (int off = 32; off; off >>= 1)
            m = fmaxf(m, __shfl_xor(m, off, 64));
        float e = __expf(nd - m);
        float t = e;
#pragma unroll
        for (int off = 32; off; off >>= 1)
            t += __shfl_xor(t, off, 64);
        out[(size_t)(q0 + q) * CN + lane] = e / t;
    }
}

extern "C" void kernel_launch(void* const* d_in, const int* in_sizes, int n_in,
                              void* d_out, int out_size, void* d_ws, size_t ws_size,
                              hipStream_t stream) {
    const float* x = (const float*)d_in[0];   // [8192, 512]
    const float* y = (const float*)d_in[1];   // [64, 5, 512]
    float* out     = (float*)d_out;           // [8192, 64]
    float* proto   = (float*)d_ws;            // [64, 512] scratch

    proto_kernel<<<(CN * DN + 255) / 256, 256, 0, stream>>>(y, proto);
    dist_kernel<<<QN / BQ, THREADS, 0, stream>>>(x, proto, out);
}

// Round 9
// 314.516 us; speedup vs baseline: 2.1766x; 2.1766x over previous
//
#include <hip/hip_runtime.h>
#include <hip/hip_bf16.h>
#include <math.h>

#define QN 8192
#define CN 64
#define SHOT 5
#define DN 512

#define THREADS 512
#define BQ 32                // queries per block -> grid 256 = 1 block/CU
#define CHUNK_D 128          // d's per staged chunk
#define NCHUNK (DN / CHUNK_D)
#define REPEATS 16           // diagnostic: measure steady-state per-pass cost

// --- proto kernel: proto[c][d] = mean over SHOT of y[c][s][d] ---
__global__ void proto_kernel(const float* __restrict__ y, float* __restrict__ proto) {
    int idx = blockIdx.x * blockDim.x + threadIdx.x;
    if (idx < CN * DN) {
        int c = idx >> 9;
        int d = idx & (DN - 1);
        float s = 0.f;
#pragma unroll
        for (int sh = 0; sh < SHOT; ++sh)
            s += y[(c * SHOT + sh) * DN + d];
        proto[idx] = s * (1.0f / SHOT);
    }
}

// --- round-7 kernel x REPEATS (zero-register-delta timing diagnostic) ---
__global__ __launch_bounds__(THREADS, 2) void dist_kernel(
        const float* __restrict__ x,
        const float* __restrict__ proto,
        float* __restrict__ out) {
    __shared__ __align__(16) float lds[24576];     // 96 KiB
    float4* xb = (float4*)lds;                     // [2][1024] f4 = 32 KiB
    float4* pb = (float4*)lds + 2048;              // [2][2048] f4 = 64 KiB

    const int tid  = threadIdx.x;
    const int lane = tid & 63;
    const int wave = __builtin_amdgcn_readfirstlane(tid >> 6);
    const int q0   = blockIdx.x * BQ;
    const int qg   = lane >> 3;
    const int cg   = lane & 7;
    const int lhi  = lane >> 5;
    const int llo  = lane & 31;

    auto issue = [&](int k) {
        const int xo = (k & 1) << 10;
        const int po = (k & 1) << 11;
#pragma unroll
        for (int tt = 0; tt < 2; ++tt) {
            int t = wave * 2 + tt;
            int q = 2 * t + lhi;
            int col = llo ^ ((q >> 2) & 7);
            const float* src = x + (size_t)(q0 + q) * DN + k * CHUNK_D + col * 4;
            __builtin_amdgcn_global_load_lds(
                (const __attribute__((address_space(1))) void*)src,
                (__attribute__((address_space(3))) void*)(xb + xo + t * 64), 16, 0, 0);
        }
#pragma unroll
        for (int tt = 0; tt < 4; ++tt) {
            int t = wave * 4 + tt;
            int c = 2 * t + lhi;
            int col = llo ^ ((c >> 3) & 7);
            const float* src = proto + (size_t)c * DN + k * CHUNK_D + col * 4;
            __builtin_amdgcn_global_load_lds(
                (const __attribute__((address_space(1))) void*)src,
                (__attribute__((address_space(3))) void*)(pb + po + t * 64), 16, 0, 0);
        }
    };

    float acc[4][8];

#pragma unroll 1
    for (int rep = 0; rep < REPEATS; ++rep) {
#pragma unroll
        for (int i = 0; i < 4; ++i)
#pragma unroll
            for (int j = 0; j < 8; ++j) acc[i][j] = 0.f;

        issue(0);
#pragma unroll 1
        for (int k = 0; k < NCHUNK; ++k) {
            if (k + 1 < NCHUNK) {
                issue(k + 1);
                asm volatile("s_waitcnt vmcnt(6)" ::: "memory");
            } else {
                asm volatile("s_waitcnt vmcnt(0)" ::: "memory");
            }
            __builtin_amdgcn_s_barrier();
            __builtin_amdgcn_sched_barrier(0);

            const float4* xc = xb + ((k & 1) << 10);
            const float4* pc = pb + ((k & 1) << 11);
#pragma unroll
            for (int ft = 0; ft < 4; ++ft) {
                const int f = wave * 4 + ft;
                float4 xf[4];
#pragma unroll
                for (int i = 0; i < 4; ++i)
                    xf[i] = xc[(qg * 4 + i) * 32 + (f ^ qg)];
#pragma unroll
                for (int j = 0; j < 8; ++j) {
                    float4 pf = pc[(cg * 8 + j) * 32 + (f ^ cg)];
#pragma unroll
                    for (int i = 0; i < 4; ++i)
                        acc[i][j] += fabsf(xf[i].x - pf.x) + fabsf(xf[i].y - pf.y)
                                   + fabsf(xf[i].z - pf.z) + fabsf(xf[i].w - pf.w);
                }
            }
            __builtin_amdgcn_sched_barrier(0);
            __builtin_amdgcn_s_barrier();
        }

        // keep this rep's results live so earlier reps aren't DCE'd (rule #17);
        // zero extra registers, zero instructions.
#pragma unroll
        for (int i = 0; i < 4; ++i)
#pragma unroll
            for (int j = 0; j < 8; ++j)
                asm volatile("" : : "v"(acc[i][j]));
    }

    // --- reduce the 8 wave-partials in LDS, then fused softmax ---
    float* red = lds;                              // [8][32][65]
#pragma unroll
    for (int i = 0; i < 4; ++i)
#pragma unroll
        for (int j = 0; j < 8; ++j)
            red[(wave * 32 + qg * 4 + i) * 65 + cg * 8 + j] = acc[i][j];
    __syncthreads();

#pragma unroll
    for (int r = 0; r < 4; ++r) {
        int q = wave * 4 + r;
        float s = 0.f;
#pragma unroll
        for (int ww = 0; ww < 8; ++ww)
            s += red[(ww * 32 + q) * 65 + lane];
        float nd = -s;
        float m = nd;
#pragma unroll
        for (int off = 32; off; off >>= 1)
            m = fmaxf(m, __shfl_xor(m, off, 64));
        float e = __expf(nd - m);
        float t = e;
#pragma unroll
        for (int off = 32; off; off >>= 1)
            t += __shfl_xor(t, off, 64);
        out[(size_t)(q0 + q) * CN + lane] = e / t;
    }
}

extern "C" void kernel_launch(void* const* d_in, const int* in_sizes, int n_in,
                              void* d_out, int out_size, void* d_ws, size_t ws_size,
                              hipStream_t stream) {
    const float* x = (const float*)d_in[0];   // [8192, 512]
    const float* y = (const float*)d_in[1];   // [64, 5, 512]
    float* out     = (float*)d_out;           // [8192, 64]
    float* proto   = (float*)d_ws;            // [64, 512] scratch

    proto_kernel<<<(CN * DN + 255) / 256, 256, 0, stream>>>(y, proto);
    dist_kernel<<<QN / BQ, THREADS, 0, stream>>>(x, proto, out);
}

// Round 10
// 293.009 us; speedup vs baseline: 2.3364x; 1.0734x over previous
//
#include <hip/hip_runtime.h>
#include <hip/hip_bf16.h>
#include <math.h>

#define QN 8192
#define CN 64
#define SHOT 5
#define DN 512

#define THREADS 1024
#define NWAVE 16
#define BQ 32               // queries per block -> grid 256 = 1 block/CU

// --- proto kernel: mean over SHOT, written PRE-SWIZZLED (m173 pattern) ---
// main kernel reads p[c] f4-col F at LDS index c*128 + (F ^ ((c>>3)&7));
// DMA is linear, so store P[c][g] at ws f4 idx c*128 + (g&~7) | ((g&7) ^ ((c>>3)&7))
__global__ void proto_kernel(const float* __restrict__ y, float* __restrict__ pws) {
    int idx = blockIdx.x * blockDim.x + threadIdx.x;   // 0 .. C*D-1
    if (idx < CN * DN) {
        int c = idx >> 9;
        int d = idx & (DN - 1);
        float s = 0.f;
#pragma unroll
        for (int sh = 0; sh < SHOT; ++sh)
            s += y[(c * SHOT + sh) * DN + d];
        int g   = d >> 2;
        int sub = d & 3;
        int gs  = (g & ~7) | ((g & 7) ^ ((c >> 3) & 7));
        pws[c * DN + gs * 4 + sub] = s * (1.0f / SHOT);
    }
}

// --- fused dist+softmax: 16 waves (4/SIMD), whole proto in LDS, x from global ---
__global__ __launch_bounds__(THREADS, 4) void dist_kernel(
        const float* __restrict__ x,
        const float* __restrict__ pws,
        float* __restrict__ out) {
    __shared__ __align__(16) float lds[CN * DN];   // 128 KiB: proto, then reduce buf
    float4* pb = (float4*)lds;                     // [64][128] f4, rows XOR-swizzled

    const int tid  = threadIdx.x;
    const int lane = tid & 63;
    const int wave = __builtin_amdgcn_readfirstlane(tid >> 6);
    const int q0   = blockIdx.x * BQ;
    const int qg   = lane >> 3;        // 0..7: q-group of 4
    const int cg   = lane & 7;         // 0..7: c-group of 8

    // stage entire swizzled proto: pure linear copy, 8 DMA instrs/thread
#pragma unroll
    for (int k = 0; k < 8; ++k) {
        int i = tid + k * THREADS;     // consecutive lanes -> consecutive 16B
        __builtin_amdgcn_global_load_lds(
            (const __attribute__((address_space(1))) void*)(pws + i * 4),
            (__attribute__((address_space(3))) void*)(pb + i), 16, 0, 0);
    }
    asm volatile("s_waitcnt vmcnt(0)" ::: "memory");
    __builtin_amdgcn_s_barrier();

    float acc[4][8];
#pragma unroll
    for (int i = 0; i < 4; ++i)
#pragma unroll
        for (int j = 0; j < 8; ++j) acc[i][j] = 0.f;

    const int F0 = wave * 8;           // this wave's 32-d slice (8 f4 cols)
#pragma unroll
    for (int ft = 0; ft < 8; ++ft) {
        const int F = F0 + ft;
        float4 xf[4];
#pragma unroll
        for (int i = 0; i < 4; ++i)    // private q-rows straight from global (L2/L3)
            xf[i] = *(const float4*)(x + (size_t)(q0 + qg * 4 + i) * DN + F * 4);
#pragma unroll
        for (int j = 0; j < 8; ++j) {
            const int c = cg * 8 + j;
            float4 pf = pb[c * 128 + (F ^ cg)];   // 8 addrs x 8-lane bcast: optimal b128
#pragma unroll
            for (int i = 0; i < 4; ++i)
                acc[i][j] += fabsf(xf[i].x - pf.x) + fabsf(xf[i].y - pf.y)
                           + fabsf(xf[i].z - pf.z) + fabsf(xf[i].w - pf.w);
        }
    }
    __builtin_amdgcn_s_barrier();      // all pb reads done before aliasing writes

    // --- fold 16 -> 8 wave-partials, then reduce + fused softmax (round-7 style) ---
    float* red = lds;                  // [8][32][65] = 66,560 B (aliases pb)
    if (wave >= 8) {
#pragma unroll
        for (int i = 0; i < 4; ++i)
#pragma unroll
            for (int j = 0; j < 8; ++j)
                red[((wave - 8) * 32 + qg * 4 + i) * 65 + cg * 8 + j] = acc[i][j];
    }
    __syncthreads();
    if (wave < 8) {
#pragma unroll
        for (int i = 0; i < 4; ++i)
#pragma unroll
            for (int j = 0; j < 8; ++j) {
                acc[i][j] += red[(wave * 32 + qg * 4 + i) * 65 + cg * 8 + j];
                red[(wave * 32 + qg * 4 + i) * 65 + cg * 8 + j] = acc[i][j];
            }
    }
    __syncthreads();

    // final: wave w handles q rows 2w, 2w+1; lane = class
#pragma unroll
    for (int r = 0; r < 2; ++r) {
        int q = wave * 2 + r;
        float s = 0.f;
#pragma unroll
        for (int ww = 0; ww < 8; ++ww)
            s += red[(ww * 32 + q) * 65 + lane];
        float nd = -s;
        float m = nd;
#pragma unroll
        for (int off = 32; off; off >>= 1)
            m = fmaxf(m, __shfl_xor(m, off, 64));
        float e = __expf(nd - m);
        float t = e;
#pragma unroll
        for (int off = 32; off; off >>= 1)
            t += __shfl_xor(t, off, 64);
        out[(size_t)(q0 + q) * CN + lane] = e / t;
    }
}

extern "C" void kernel_launch(void* const* d_in, const int* in_sizes, int n_in,
                              void* d_out, int out_size, void* d_ws, size_t ws_size,
                              hipStream_t stream) {
    const float* x = (const float*)d_in[0];   // [8192, 512]
    const float* y = (const float*)d_in[1];   // [64, 5, 512]
    float* out     = (float*)d_out;           // [8192, 64]
    float* pws     = (float*)d_ws;            // [64, 512] swizzled proto scratch

    proto_kernel<<<(CN * DN + 255) / 256, 256, 0, stream>>>(y, pws);
    dist_kernel<<<QN / BQ, THREADS, 0, stream>>>(x, pws, out);
}

// Round 11
// 292.692 us; speedup vs baseline: 2.3389x; 1.0011x over previous
//
#include <hip/hip_runtime.h>
#include <hip/hip_bf16.h>
#include <math.h>

#define QN 8192
#define CN 64
#define SHOT 5
#define DN 512

#define THREADS 1024
#define NWAVE 16
#define BQ 32               // queries per block -> grid 256 = 1 block/CU

// --- proto kernel: mean over SHOT, written PRE-SWIZZLED (m173 pattern) ---
// main kernel reads p[c] f4-col F at LDS index c*128 + (F ^ ((c>>3)&7));
// DMA is linear, so store P[c][g] at ws f4 idx c*128 + (g&~7) | ((g&7) ^ ((c>>3)&7))
__global__ void proto_kernel(const float* __restrict__ y, float* __restrict__ pws) {
    int idx = blockIdx.x * blockDim.x + threadIdx.x;   // 0 .. C*D-1
    if (idx < CN * DN) {
        int c = idx >> 9;
        int d = idx & (DN - 1);
        float s = 0.f;
#pragma unroll
        for (int sh = 0; sh < SHOT; ++sh)
            s += y[(c * SHOT + sh) * DN + d];
        int g   = d >> 2;
        int sub = d & 3;
        int gs  = (g & ~7) | ((g & 7) ^ ((c >> 3) & 7));
        pws[c * DN + gs * 4 + sub] = s * (1.0f / SHOT);
    }
}

// --- fused dist+softmax: 16 waves (4/SIMD), whole proto in LDS, x from global ---
// waves_per_eu(4,4): pin VGPR budget to 128 so the ~100-reg working set
// does NOT spill (round 10: launch_bounds min-only -> compiler chose 64 + spilled).
__global__ __launch_bounds__(THREADS)
__attribute__((amdgpu_waves_per_eu(4, 4))) void dist_kernel(
        const float* __restrict__ x,
        const float* __restrict__ pws,
        float* __restrict__ out) {
    __shared__ __align__(16) float lds[CN * DN];   // 128 KiB: proto, then reduce buf
    float4* pb = (float4*)lds;                     // [64][128] f4, rows XOR-swizzled

    const int tid  = threadIdx.x;
    const int lane = tid & 63;
    const int wave = __builtin_amdgcn_readfirstlane(tid >> 6);
    const int q0   = blockIdx.x * BQ;
    const int qg   = lane >> 3;        // 0..7: q-group of 4
    const int cg   = lane & 7;         // 0..7: c-group of 8

    // stage entire swizzled proto: pure linear copy, 8 DMA instrs/thread
#pragma unroll
    for (int k = 0; k < 8; ++k) {
        int i = tid + k * THREADS;     // consecutive lanes -> consecutive 16B
        __builtin_amdgcn_global_load_lds(
            (const __attribute__((address_space(1))) void*)(pws + i * 4),
            (__attribute__((address_space(3))) void*)(pb + i), 16, 0, 0);
    }
    asm volatile("s_waitcnt vmcnt(0)" ::: "memory");
    __builtin_amdgcn_s_barrier();

    float acc[4][8];
#pragma unroll
    for (int i = 0; i < 4; ++i)
#pragma unroll
        for (int j = 0; j < 8; ++j) acc[i][j] = 0.f;

    const int F0 = wave * 8;           // this wave's 32-d slice (8 f4 cols)
#pragma unroll
    for (int ft = 0; ft < 8; ++ft) {
        const int F = F0 + ft;
        float4 xf[4];
#pragma unroll
        for (int i = 0; i < 4; ++i)    // private q-rows straight from global (L2/L3)
            xf[i] = *(const float4*)(x + (size_t)(q0 + qg * 4 + i) * DN + F * 4);
#pragma unroll
        for (int j = 0; j < 8; ++j) {
            const int c = cg * 8 + j;
            float4 pf = pb[c * 128 + (F ^ cg)];   // 8 addrs x 8-lane bcast: optimal b128
#pragma unroll
            for (int i = 0; i < 4; ++i)
                acc[i][j] += fabsf(xf[i].x - pf.x) + fabsf(xf[i].y - pf.y)
                           + fabsf(xf[i].z - pf.z) + fabsf(xf[i].w - pf.w);
        }
    }
    __builtin_amdgcn_s_barrier();      // all pb reads done before aliasing writes

    // --- fold 16 -> 8 wave-partials, then reduce + fused softmax ---
    float* red = lds;                  // [8][32][65] = 66,560 B (aliases pb)
    if (wave >= 8) {
#pragma unroll
        for (int i = 0; i < 4; ++i)
#pragma unroll
            for (int j = 0; j < 8; ++j)
                red[((wave - 8) * 32 + qg * 4 + i) * 65 + cg * 8 + j] = acc[i][j];
    }
    __syncthreads();
    if (wave < 8) {
#pragma unroll
        for (int i = 0; i < 4; ++i)
#pragma unroll
            for (int j = 0; j < 8; ++j) {
                acc[i][j] += red[(wave * 32 + qg * 4 + i) * 65 + cg * 8 + j];
                red[(wave * 32 + qg * 4 + i) * 65 + cg * 8 + j] = acc[i][j];
            }
    }
    __syncthreads();

    // final: wave w handles q rows 2w, 2w+1; lane = class
#pragma unroll
    for (int r = 0; r < 2; ++r) {
        int q = wave * 2 + r;
        float s = 0.f;
#pragma unroll
        for (int ww = 0; ww < 8; ++ww)
            s += red[(ww * 32 + q) * 65 + lane];
        float nd = -s;
        float m = nd;
#pragma unroll
        for (int off = 32; off; off >>= 1)
            m = fmaxf(m, __shfl_xor(m, off, 64));
        float e = __expf(nd - m);
        float t = e;
#pragma unroll
        for (int off = 32; off; off >>= 1)
            t += __shfl_xor(t, off, 64);
        out[(size_t)(q0 + q) * CN + lane] = e / t;
    }
}

extern "C" void kernel_launch(void* const* d_in, const int* in_sizes, int n_in,
                              void* d_out, int out_size, void* d_ws, size_t ws_size,
                              hipStream_t stream) {
    const float* x = (const float*)d_in[0];   // [8192, 512]
    const float* y = (const float*)d_in[1];   // [64, 5, 512]
    float* out     = (float*)d_out;           // [8192, 64]
    float* pws     = (float*)d_ws;            // [64, 512] swizzled proto scratch

    proto_kernel<<<(CN * DN + 255) / 256, 256, 0, stream>>>(y, pws);
    dist_kernel<<<QN / BQ, THREADS, 0, stream>>>(x, pws, out);
}

// Round 12
// 155.341 us; speedup vs baseline: 4.4069x; 1.8842x over previous
//
#include <hip/hip_runtime.h>
#include <hip/hip_bf16.h>
#include <math.h>

#define QN 8192
#define CN 64
#define SHOT 5
#define DN 512

#define THREADS 512
#define BQ 16                 // queries/block -> grid 512 = 2 blocks/CU (64KB LDS)
#define HALF_D 256            // proto staged in two 64 KB halves
#define F4H (HALF_D / 4)      // 64 f4 per class-row per half

// --- proto kernel: mean over SHOT, PRE-SWIZZLED halves (m173: linear DMA dest) ---
// reader wants P[c][F] at pb[c*64 + (F&~7)|((F&7)^((c>>2)&7))]
__global__ void proto_kernel(const float* __restrict__ y, float* __restrict__ pws) {
    int idx = blockIdx.x * blockDim.x + threadIdx.x;   // 0 .. C*D-1
    if (idx < CN * DN) {
        int c = idx >> 9;
        int d = idx & (DN - 1);
        float s = 0.f;
#pragma unroll
        for (int sh = 0; sh < SHOT; ++sh)
            s += y[(c * SHOT + sh) * DN + d];
        int half = d >> 8;
        int g    = (d >> 2) & (F4H - 1);
        int sub  = d & 3;
        int s8   = (c >> 2) & 7;
        int gs   = (g & ~7) | ((g & 7) ^ s8);
        pws[(half * CN + c) * HALF_D + gs * 4 + sub] = s * (1.0f / SHOT);
    }
}

// --- fused dist+softmax: 512 thr, 2 blocks/CU, proto in 2 LDS halves ---
__global__ __launch_bounds__(THREADS, 4) void dist_kernel(
        const float* __restrict__ x,
        const float* __restrict__ pws,
        float* __restrict__ out) {
    __shared__ __align__(16) float lds[CN * HALF_D];   // 64 KiB
    float4* pb = (float4*)lds;                         // [64][64] f4, col-swizzled

    const int tid  = threadIdx.x;
    const int lane = tid & 63;
    const int wave = __builtin_amdgcn_readfirstlane(tid >> 6);
    const int q0   = blockIdx.x * BQ;
    const int qg   = lane >> 4;        // 0..3 : q-group of 4
    const int cg   = lane & 15;        // 0..15: c-group of 4
    const int s8   = cg & 7;           // col swizzle for my classes

    float acc[4][4];
#pragma unroll
    for (int i = 0; i < 4; ++i)
#pragma unroll
        for (int j = 0; j < 4; ++j) acc[i][j] = 0.f;

#pragma unroll 1
    for (int half = 0; half < 2; ++half) {
        // stage this 64 KB half: pure linear DMA copy, 8 instrs/thread
        const float* src = pws + (size_t)half * CN * HALF_D;
#pragma unroll
        for (int k = 0; k < 8; ++k) {
            int i = tid + k * THREADS;
            __builtin_amdgcn_global_load_lds(
                (const __attribute__((address_space(1))) void*)(src + i * 4),
                (__attribute__((address_space(3))) void*)(pb + i), 16, 0, 0);
        }
        asm volatile("s_waitcnt vmcnt(0)" ::: "memory");
        __syncthreads();

        const int F0 = wave * 8;       // wave's 8-f4 (32-d) slice of this half
        const float* xbase = x + (size_t)q0 * DN + half * HALF_D;
#pragma unroll
        for (int ft = 0; ft < 8; ++ft) {
            float4 xf[4];
#pragma unroll
            for (int i = 0; i < 4; ++i)   // private q-rows, straight from global
                xf[i] = *(const float4*)(xbase + (size_t)(qg * 4 + i) * DN + (F0 + ft) * 4);
#pragma unroll
            for (int j = 0; j < 4; ++j) {
                const int c = cg * 4 + j;
                float4 pf = pb[c * F4H + F0 + (ft ^ s8)];   // 16 addrs x 4-bcast, 2/bank
#pragma unroll
                for (int i = 0; i < 4; ++i)
                    acc[i][j] += fabsf(xf[i].x - pf.x) + fabsf(xf[i].y - pf.y)
                               + fabsf(xf[i].z - pf.z) + fabsf(xf[i].w - pf.w);
            }
        }
        __syncthreads();               // all reads done before next half / epilogue
    }

    // --- reduce 8 wave-partials in LDS (aliases pb), then fused softmax ---
    float* red = lds;                  // [8][16][65] = 33,280 B
#pragma unroll
    for (int i = 0; i < 4; ++i)
#pragma unroll
        for (int j = 0; j < 4; ++j)
            red[(wave * BQ + qg * 4 + i) * 65 + cg * 4 + j] = acc[i][j];
    __syncthreads();

    // wave w handles q rows 2w, 2w+1; lane = class
#pragma unroll
    for (int r = 0; r < 2; ++r) {
        int q = wave * 2 + r;
        float s = 0.f;
#pragma unroll
        for (int ww = 0; ww < 8; ++ww)
            s += red[(ww * BQ + q) * 65 + lane];
        float nd = -s;
        float m = nd;
#pragma unroll
        for (int off = 32; off; off >>= 1)
            m = fmaxf(m, __shfl_xor(m, off, 64));
        float e = __expf(nd - m);
        float t = e;
#pragma unroll
        for (int off = 32; off; off >>= 1)
            t += __shfl_xor(t, off, 64);
        out[(size_t)(q0 + q) * CN + lane] = e / t;
    }
}

extern "C" void kernel_launch(void* const* d_in, const int* in_sizes, int n_in,
                              void* d_out, int out_size, void* d_ws, size_t ws_size,
                              hipStream_t stream) {
    const float* x = (const float*)d_in[0];   // [8192, 512]
    const float* y = (const float*)d_in[1];   // [64, 5, 512]
    float* out     = (float*)d_out;           // [8192, 64]
    float* pws     = (float*)d_ws;            // [2][64][256] swizzled proto halves

    proto_kernel<<<(CN * DN + 255) / 256, 256, 0, stream>>>(y, pws);
    dist_kernel<<<QN / BQ, THREADS, 0, stream>>>(x, pws, out);
}

// Round 13
// 59.292 us; speedup vs baseline: 11.5459x; 2.6200x over previous
//
#include <hip/hip_runtime.h>
#include <hip/hip_bf16.h>
#include <math.h>

#define QN 8192
#define CN 64
#define SHOT 5
#define DN 512

#define THREADS 512
#define BQ 16                 // queries/block -> grid 512 = 2 blocks/CU (64KB LDS)
#define HALF_D 256            // proto staged in two 64 KB halves
#define F4H (HALF_D / 4)      // 64 f4 per class-row per half

// --- proto kernel: mean over SHOT, PRE-SWIZZLED halves (m173: linear DMA dest) ---
// reader wants P[c][F] at pb[c*64 + (F&~7)|((F&7)^((c>>2)&7))]
__global__ void proto_kernel(const float* __restrict__ y, float* __restrict__ pws) {
    int idx = blockIdx.x * blockDim.x + threadIdx.x;   // 0 .. C*D-1
    if (idx < CN * DN) {
        int c = idx >> 9;
        int d = idx & (DN - 1);
        float s = 0.f;
#pragma unroll
        for (int sh = 0; sh < SHOT; ++sh)
            s += y[(c * SHOT + sh) * DN + d];
        int half = d >> 8;
        int g    = (d >> 2) & (F4H - 1);
        int sub  = d & 3;
        int s8   = (c >> 2) & 7;
        int gs   = (g & ~7) | ((g & 7) ^ s8);
        pws[(half * CN + c) * HALF_D + gs * 4 + sub] = s * (1.0f / SHOT);
    }
}

// --- fused dist+softmax: 512 thr, 2 blocks/CU, proto in 2 LDS halves ---
// launch_bounds 2nd arg = MIN WAVES PER EU (not blocks/CU!). 2 -> VGPR cap >=128,
// no spill (round 12 used 4 -> 64-reg cap -> 400 MB scratch spill).
__global__ __launch_bounds__(THREADS, 2) void dist_kernel(
        const float* __restrict__ x,
        const float* __restrict__ pws,
        float* __restrict__ out) {
    __shared__ __align__(16) float lds[CN * HALF_D];   // 64 KiB
    float4* pb = (float4*)lds;                         // [64][64] f4, col-swizzled

    const int tid  = threadIdx.x;
    const int lane = tid & 63;
    const int wave = __builtin_amdgcn_readfirstlane(tid >> 6);
    const int q0   = blockIdx.x * BQ;
    const int qg   = lane >> 4;        // 0..3 : q-group of 4
    const int cg   = lane & 15;        // 0..15: c-group of 4
    const int s8   = cg & 7;           // col swizzle for my classes

    float acc[4][4];
#pragma unroll
    for (int i = 0; i < 4; ++i)
#pragma unroll
        for (int j = 0; j < 4; ++j) acc[i][j] = 0.f;

#pragma unroll 1
    for (int half = 0; half < 2; ++half) {
        // stage this 64 KB half: pure linear DMA copy, 8 instrs/thread
        const float* src = pws + (size_t)half * CN * HALF_D;
#pragma unroll
        for (int k = 0; k < 8; ++k) {
            int i = tid + k * THREADS;
            __builtin_amdgcn_global_load_lds(
                (const __attribute__((address_space(1))) void*)(src + i * 4),
                (__attribute__((address_space(3))) void*)(pb + i), 16, 0, 0);
        }
        asm volatile("s_waitcnt vmcnt(0)" ::: "memory");
        __syncthreads();

        const int F0 = wave * 8;       // wave's 8-f4 (32-d) slice of this half
        const float* xbase = x + (size_t)q0 * DN + half * HALF_D;
#pragma unroll
        for (int ft = 0; ft < 8; ++ft) {
            float4 xf[4];
#pragma unroll
            for (int i = 0; i < 4; ++i)   // private q-rows, straight from global
                xf[i] = *(const float4*)(xbase + (size_t)(qg * 4 + i) * DN + (F0 + ft) * 4);
#pragma unroll
            for (int j = 0; j < 4; ++j) {
                const int c = cg * 4 + j;
                float4 pf = pb[c * F4H + F0 + (ft ^ s8)];   // 16 addrs x 4-bcast, 2/bank
#pragma unroll
                for (int i = 0; i < 4; ++i)
                    acc[i][j] += fabsf(xf[i].x - pf.x) + fabsf(xf[i].y - pf.y)
                               + fabsf(xf[i].z - pf.z) + fabsf(xf[i].w - pf.w);
            }
        }
        __syncthreads();               // all reads done before next half / epilogue
    }

    // --- reduce 8 wave-partials in LDS (aliases pb), then fused softmax ---
    float* red = lds;                  // [8][16][65] = 33,280 B
#pragma unroll
    for (int i = 0; i < 4; ++i)
#pragma unroll
        for (int j = 0; j < 4; ++j)
            red[(wave * BQ + qg * 4 + i) * 65 + cg * 4 + j] = acc[i][j];
    __syncthreads();

    // wave w handles q rows 2w, 2w+1; lane = class
#pragma unroll
    for (int r = 0; r < 2; ++r) {
        int q = wave * 2 + r;
        float s = 0.f;
#pragma unroll
        for (int ww = 0; ww < 8; ++ww)
            s += red[(ww * BQ + q) * 65 + lane];
        float nd = -s;
        float m = nd;
#pragma unroll
        for (int off = 32; off; off >>= 1)
            m = fmaxf(m, __shfl_xor(m, off, 64));
        float e = __expf(nd - m);
        float t = e;
#pragma unroll
        for (int off = 32; off; off >>= 1)
            t += __shfl_xor(t, off, 64);
        out[(size_t)(q0 + q) * CN + lane] = e / t;
    }
}

extern "C" void kernel_launch(void* const* d_in, const int* in_sizes, int n_in,
                              void* d_out, int out_size, void* d_ws, size_t ws_size,
                              hipStream_t stream) {
    const float* x = (const float*)d_in[0];   // [8192, 512]
    const float* y = (const float*)d_in[1];   // [64, 5, 512]
    float* out     = (float*)d_out;           // [8192, 64]
    float* pws     = (float*)d_ws;            // [2][64][256] swizzled proto halves

    proto_kernel<<<(CN * DN + 255) / 256, 256, 0, stream>>>(y, pws);
    dist_kernel<<<QN / BQ, THREADS, 0, stream>>>(x, pws, out);
}